// Round 2
// baseline (1036.079 us; speedup 1.0000x reference)
//
#include <hip/hip_runtime.h>
#include <stdint.h>

// ---------- types / helpers ----------
typedef __bf16 bf16x8 __attribute__((ext_vector_type(8)));
typedef float  f32x4  __attribute__((ext_vector_type(4)));

// convert 8 contiguous fp32 -> bf16x8 (RNE via clang __bf16 cast)
__device__ __forceinline__ bf16x8 cvt8(const float* __restrict__ p) {
    float4 lo = *(const float4*)p;
    float4 hi = *(const float4*)(p + 4);
    bf16x8 r;
    r[0] = (__bf16)lo.x; r[1] = (__bf16)lo.y; r[2] = (__bf16)lo.z; r[3] = (__bf16)lo.w;
    r[4] = (__bf16)hi.x; r[5] = (__bf16)hi.y; r[6] = (__bf16)hi.z; r[7] = (__bf16)hi.w;
    return r;
}

// pair index for i<j over A=20 agents, lexicographic (matches np.unique of sorted pairs)
__device__ __forceinline__ int pidx(int i, int j) {
    return i * 19 - (i * (i - 1)) / 2 + (j - i - 1);
}

// ---------- GEMM: C[M,N] = rowmap(X)[M,K] @ W[N,K]^T + bias, fp32 in (or bf16 ws), fp32/bf16 out
// MODE 0: glob  — X row r at offset r*81920        (x[:, :, 0, :], stride A*NIN)
// MODE 1: loc   — X row r at ((r/19)*20 + r%19 +1)*4096  (x[:, :, 1:, :])
// MODE 2: plain — X row r at r*K
// Tile: BM=64, BN=64, BK=32; 256 threads = 4 waves; wave w -> 32x32 quadrant.
template <int MODE, bool A_BF16, bool OUT_BF16>
__global__ __launch_bounds__(256) void gemm_bias_kernel(
    const void* __restrict__ Xv,
    const float* __restrict__ W,      // (N, K) fp32
    const float* __restrict__ bias,   // (N)    fp32
    void* __restrict__ Cv,
    int M, int N, int K)
{
    __shared__ __bf16 As[64][40];  // +8 pad keeps 16B alignment; 2-way bank alias is free
    __shared__ __bf16 Bs[64][40];

    const int tid  = threadIdx.x;
    const int srow = tid >> 2;          // 0..63 staging row
    const int scol = (tid & 3) << 3;    // 0,8,16,24 (elements)

    int gmrow = (int)blockIdx.y * 64 + srow;
    int rA = gmrow < M ? gmrow : M - 1;               // clamp; OOB rows never stored
    size_t aoff;
    if (MODE == 0)      aoff = (size_t)rA * 81920;
    else if (MODE == 1) aoff = ((size_t)(rA / 19) * 20 + (size_t)(rA % 19) + 1) * 4096;
    else                aoff = (size_t)rA * (size_t)K;
    const float*  aptrF = (const float*)Xv  + aoff + scol;   // used when !A_BF16
    const __bf16* aptrH = (const __bf16*)Xv + aoff + scol;   // used when  A_BF16
    const float*  bptr  = W + (size_t)((int)blockIdx.x * 64 + srow) * (size_t)K + scol;

    const int w    = tid >> 6;          // wave 0..3
    const int lane = tid & 63;
    const int wm   = (w >> 1) * 32;     // wave row offset in tile
    const int wn   = (w & 1) * 32;      // wave col offset in tile
    const int l    = lane & 15;
    const int qk   = lane >> 4;         // quad 0..3
    const int q8   = qk * 8;            // fragment k-offset (elements)

    f32x4 acc00 = {}, acc01 = {}, acc10 = {}, acc11 = {};

    for (int k0 = 0; k0 < K; k0 += 32) {
        bf16x8 av, bv;
        if (A_BF16) av = *(const bf16x8*)(aptrH + k0);
        else        av = cvt8(aptrF + k0);
        bv = cvt8(bptr + k0);
        __syncthreads();
        *(bf16x8*)&As[srow][scol] = av;
        *(bf16x8*)&Bs[srow][scol] = bv;
        __syncthreads();
        bf16x8 a0 = *(const bf16x8*)&As[wm + l][q8];
        bf16x8 a1 = *(const bf16x8*)&As[wm + 16 + l][q8];
        bf16x8 b0 = *(const bf16x8*)&Bs[wn + l][q8];
        bf16x8 b1 = *(const bf16x8*)&Bs[wn + 16 + l][q8];
        acc00 = __builtin_amdgcn_mfma_f32_16x16x32_bf16(a0, b0, acc00, 0, 0, 0);
        acc01 = __builtin_amdgcn_mfma_f32_16x16x32_bf16(a0, b1, acc01, 0, 0, 0);
        acc10 = __builtin_amdgcn_mfma_f32_16x16x32_bf16(a1, b0, acc10, 0, 0, 0);
        acc11 = __builtin_amdgcn_mfma_f32_16x16x32_bf16(a1, b1, acc11, 0, 0, 0);
    }

    // epilogue: C/D layout col=lane&15, row=(lane>>4)*4+reg
    const int colBase = (int)blockIdx.x * 64;
    const int rowBase = (int)blockIdx.y * 64;
    const float bias0 = bias[colBase + wn + l];
    const float bias1 = bias[colBase + wn + 16 + l];
    #pragma unroll
    for (int i = 0; i < 2; ++i) {
        f32x4 aj0 = (i == 0) ? acc00 : acc10;
        f32x4 aj1 = (i == 0) ? acc01 : acc11;
        #pragma unroll
        for (int r = 0; r < 4; ++r) {
            int row = rowBase + wm + i * 16 + qk * 4 + r;
            if (row < M) {
                size_t base = (size_t)row * (size_t)N + colBase + wn;
                float v0 = aj0[r] + bias0;
                float v1 = aj1[r] + bias1;
                if (OUT_BF16) {
                    ((__bf16*)Cv)[base + l]      = (__bf16)v0;
                    ((__bf16*)Cv)[base + 16 + l] = (__bf16)v1;
                } else {
                    ((float*)Cv)[base + l]      = v0;
                    ((float*)Cv)[base + 16 + l] = v1;
                }
            }
        }
    }
}

// ---------- phys stage 1: h1[g*190+p, c] = relu(concat(wcf[g,i],wcf[g,j]) . W1[c] + b1[c])
__global__ __launch_bounds__(256) void phys1_kernel(
    const float* __restrict__ wcf,   // (1000, 20*13) fp32
    const float* __restrict__ W1,    // (256, 26) fp32
    const float* __restrict__ b1,    // (256) fp32
    __bf16* __restrict__ h1)         // (1000*190, 256) bf16
{
    __shared__ float fs[260];
    const int g = blockIdx.x;
    const int c = threadIdx.x;
    for (int i = c; i < 260; i += 256) fs[i] = wcf[g * 260 + i];
    float wrow[26];
    #pragma unroll
    for (int k = 0; k < 26; ++k) wrow[k] = W1[c * 26 + k];
    const float bias = b1[c];
    __syncthreads();

    __bf16* out = h1 + (size_t)g * 190 * 256 + c;
    int p = 0;
    for (int i = 0; i < 20; ++i) {
        for (int j = i + 1; j < 20; ++j, ++p) {
            float s = bias;
            #pragma unroll
            for (int k = 0; k < 13; ++k) s += wrow[k]      * fs[i * 13 + k];
            #pragma unroll
            for (int k = 0; k < 13; ++k) s += wrow[13 + k] * fs[j * 13 + k];
            out[(size_t)p * 256] = (__bf16)(s > 0.f ? s : 0.f);
        }
    }
}

// ---------- segment max: agent[g,a,c] = max over 19 pairs containing a of phys[g,p,c]
__global__ __launch_bounds__(256) void segmax_kernel(
    const __bf16* __restrict__ phys,  // (1000*190, 256) bf16
    float* __restrict__ agent)        // (1000*20, 256) fp32
{
    const int a = blockIdx.x;   // 0..19
    const int g = blockIdx.y;   // 0..999
    const int c = threadIdx.x;
    const __bf16* base = phys + (size_t)g * 190 * 256 + c;
    float m = -3.4e38f;
    #pragma unroll
    for (int j = 0; j < 20; ++j) {
        if (j == a) continue;
        int p = (j > a) ? pidx(a, j) : pidx(j, a);
        float v = (float)base[(size_t)p * 256];
        m = v > m ? v : m;
    }
    agent[((size_t)g * 20 + a) * 256 + c] = m;
}

// ---------- launch ----------
extern "C" void kernel_launch(void* const* d_in, const int* in_sizes, int n_in,
                              void* d_out, int out_size, void* d_ws, size_t ws_size,
                              hipStream_t stream)
{
    const float* x   = (const float*)d_in[0];
    const float* wcf = (const float*)d_in[1];
    const float* Wg  = (const float*)d_in[2];
    const float* bg  = (const float*)d_in[3];
    const float* Wl  = (const float*)d_in[4];
    const float* bl  = (const float*)d_in[5];
    const float* W1  = (const float*)d_in[6];
    const float* b1  = (const float*)d_in[7];
    const float* W3  = (const float*)d_in[8];
    const float* b3  = (const float*)d_in[9];

    float* out   = (float*)d_out;
    float* glob  = out;                          // (1000, 1024)
    float* loc   = out + 1024000;                // (1000, 19, 512)
    float* agent = out + 1024000 + 9728000;      // (1000, 20, 256)

    __bf16* h1   = (__bf16*)d_ws;                    // (190000, 256) bf16
    __bf16* phys = h1 + (size_t)190000 * 256;        // (190000, 256) bf16

    // glob: M=1000 N=1024 K=4096  (fp32 in, fp32 out)
    gemm_bias_kernel<0, false, false><<<dim3(1024 / 64, (1000 + 63) / 64), 256, 0, stream>>>(
        x, Wg, bg, glob, 1000, 1024, 4096);
    // loc: M=19000 N=512 K=4096  (fp32 in, fp32 out)
    gemm_bias_kernel<1, false, false><<<dim3(512 / 64, (19000 + 63) / 64), 256, 0, stream>>>(
        x, Wl, bl, loc, 19000, 512, 4096);
    // phys stage 1 (relu, K=26): fp32 in, bf16 out to ws
    phys1_kernel<<<1000, 256, 0, stream>>>(wcf, W1, b1, h1);
    // phys stage 2: M=190000 N=256 K=256  (bf16 A from ws, fp32 W3 converted, bf16 out to ws)
    gemm_bias_kernel<2, true, true><<<dim3(256 / 64, (190000 + 63) / 64), 256, 0, stream>>>(
        h1, W3, b3, phys, 190000, 256, 256);
    // per-agent max over 19 pairs: bf16 in, fp32 out
    segmax_kernel<<<dim3(20, 1000), 256, 0, stream>>>(phys, agent);
}